// Round 1
// baseline (307.276 us; speedup 1.0000x reference)
//
#include <hip/hip_runtime.h>

#define HIDDEN 768
#define VOCAB  32000
#define HS1    128
#define NSTAGE 24          // 24 stages x 32 k (one MFMA K-step per stage)

typedef __attribute__((ext_vector_type(8))) short bf16x8;
typedef __attribute__((ext_vector_type(4))) float f32x4;

// fp32 -> bf16 bits, round-to-nearest-even
__device__ __forceinline__ unsigned short f2bf(float f) {
    union { float f; unsigned u; } x; x.f = f;
    unsigned r = x.u + 0x7fffu + ((x.u >> 16) & 1u);
    return (unsigned short)(r >> 16);
}

// Pack W1[VOCAB:VOCAB+768, 0:128] into bf16 MFMA B-fragment order.
// Bp[((ks*8+nt)*64+lane)*8+j] = B[k=ks*32+(lane>>4)*8+j][n=nt*16+(lane&15)].
__global__ void pack_b_kernel(const float* __restrict__ W1,
                              unsigned short* __restrict__ Bp) {
    int tid = blockIdx.x * 256 + threadIdx.x;   // 0 .. 98303
    float v = W1[(size_t)VOCAB * HS1 + tid];
    int k = tid >> 7;                            // 0..767
    int n = tid & 127;
    int ks = k >> 5, kr = k & 31;
    int quad = kr >> 3, j = kr & 7;
    int nt = n >> 4, c = n & 15;
    int lane = quad * 16 + c;
    Bp[(((ks * 8 + nt) * 64 + lane) << 3) + j] = f2bf(v);
}

// One wave = 32 token rows (2 m-tiles) x N=128 (8 n-tiles), K=768.
// R6 change: hs0 LDS staging removed — A-fragments are loaded DIRECTLY from
// global in fragment order (lane -> row=col(+16), bytes [quad*32, quad*32+32)).
// Per instruction the wave covers 16 contiguous 128-B row chunks; the lo/hi
// load pair fully consumes every 64-B line, so HBM efficiency matches the old
// coalesced staging while deleting the ds_write/ds_read/lgkmcnt chain.
// Register double-buffer (gA/gB) keeps 2 stages (8 KB/wave, 64 KB/CU) of HBM
// loads in flight, same depth as before.
// The freed LDS now caches the 32 W1 token rows per wave (16 KB), filled by
// fire-and-forget global_load_lds issued at t=0 and consumed in the epilogue —
// hides the previously-serialized scattered-gather tail under the K-loop.
__launch_bounds__(256, 2)
__global__ void classifier_kernel(const int* __restrict__ tk,
                                  const float* __restrict__ hs0,
                                  const float* __restrict__ W1,
                                  const float* __restrict__ b1,
                                  const float* __restrict__ W2,
                                  const float* __restrict__ b2,
                                  const unsigned short* __restrict__ Bp,
                                  float* __restrict__ out) {
    __shared__ float w1c[4][32][HS1];   // 64 KB: per-wave W1 token-row cache

    const int lane = threadIdx.x & 63;
    const int wave = threadIdx.x >> 6;      // 0..3
    const int quad = lane >> 4;             // 0..3
    const int col  = lane & 15;             // 0..15
    const int row0 = (blockIdx.x * 4 + wave) * 32;

    // Epilogue constants loaded up-front (oldest vmem; drained by the first
    // A-wait long before use — removes them from the tail).
    float b1v[8], w2v[8];
#pragma unroll
    for (int nt = 0; nt < 8; ++nt) {
        b1v[nt] = b1[nt * 16 + col];
        w2v[nt] = W2[nt * 16 + col];
    }
    const int mytok = tk[row0 + (lane & 31)];

    f32x4 acc[2][8];
#pragma unroll
    for (int mt = 0; mt < 2; ++mt)
#pragma unroll
        for (int nt = 0; nt < 8; ++nt)
            acc[mt][nt] = (f32x4){0.f, 0.f, 0.f, 0.f};

    // Direct fragment-order A loads: lane -> hs0[row0+col(+16)][s*32+quad*8 ..+7]
    const float* aP0 = hs0 + (size_t)(row0 + col) * HIDDEN + quad * 8;
    const float* aP1 = aP0 + (size_t)16 * HIDDEN;
    f32x4 gA[4], gB[4];
    auto loadA = [&](f32x4* a, int s) {
        const float* p0 = aP0 + s * 32;
        const float* p1 = aP1 + s * 32;
        a[0] = __builtin_nontemporal_load((const f32x4*)p0);
        a[1] = __builtin_nontemporal_load((const f32x4*)(p0 + 4));
        a[2] = __builtin_nontemporal_load((const f32x4*)p1);
        a[3] = __builtin_nontemporal_load((const f32x4*)(p1 + 4));
    };

    const unsigned short* pb0 = Bp + lane * 8;
    auto loadB = [&](int kstep, bf16x8* b) {
        const unsigned short* pb = pb0 + kstep * 4096;
#pragma unroll
        for (int nt = 0; nt < 4; ++nt) {
            b[nt]     = *(const bf16x8*)(pb + nt * 512);
            b[nt + 4] = *(const bf16x8*)(pb + 2048 + nt * 512);
        }
    };

    auto cvt8 = [&](f32x4 lo, f32x4 hi) {
        bf16x8 r;
        r[0] = (short)f2bf(lo[0]); r[1] = (short)f2bf(lo[1]);
        r[2] = (short)f2bf(lo[2]); r[3] = (short)f2bf(lo[3]);
        r[4] = (short)f2bf(hi[0]); r[5] = (short)f2bf(hi[1]);
        r[6] = (short)f2bf(hi[2]); r[7] = (short)f2bf(hi[3]);
        return r;
    };

    // Prologue: A-stages 0,1 and B k-step 0 in flight.
    bf16x8 bfrA[8], bfrB[8];
    loadA(gA, 0);
    loadA(gB, 1);
    loadB(0, bfrA);

    // W1 token-row gathers -> LDS, fire-and-forget. Issued AFTER the prologue
    // loads so the stage-0 waits (on A0/B0, which are older) don't drain them.
    // Instr p covers rows 2p (lanes 0-31) and 2p+1 (lanes 32-63): HW writes
    // lds_base + lane*16; source is per-lane W1[tok]*512 + (lane&31)*16.
    {
        float* dst0 = &w1c[wave][0][0];
#pragma unroll
        for (int p = 0; p < 16; ++p) {
            int t = __shfl(mytok, 2 * p + (lane >> 5));
            const float* src = W1 + (size_t)t * HS1 + (lane & 31) * 4;
            __builtin_amdgcn_global_load_lds(
                (const __attribute__((address_space(1))) void*)src,
                (__attribute__((address_space(3))) void*)(dst0 + p * 2 * HS1),
                16, 0, 0);
        }
    }

    // Per stage: issue next B (L2-hot), convert current A, reload same A regs
    // with stage s+2 (WAR on consumed regs), 16 MFMA. No LDS, no barriers.
    auto stage_body = [&](int s, f32x4* a, const bf16x8* bc, bf16x8* bn) {
        if (s + 1 < NSTAGE) loadB(s + 1, bn);
        bf16x8 af0 = cvt8(a[0], a[1]);
        bf16x8 af1 = cvt8(a[2], a[3]);
        if (s + 2 < NSTAGE) loadA(a, s + 2);
#pragma unroll
        for (int nt = 0; nt < 8; ++nt) {
            acc[0][nt] = __builtin_amdgcn_mfma_f32_16x16x32_bf16(af0, bc[nt], acc[0][nt], 0, 0, 0);
            acc[1][nt] = __builtin_amdgcn_mfma_f32_16x16x32_bf16(af1, bc[nt], acc[1][nt], 0, 0, 0);
        }
    };

#pragma unroll 1
    for (int s = 0; s < NSTAGE; s += 2) {
        stage_body(s,     gA, bfrA, bfrB);
        stage_body(s + 1, gB, bfrB, bfrA);
    }

    // Ensure the global_load_lds gathers have landed (belt-and-suspenders;
    // the K-loop's vmcnt waits have almost certainly drained them already).
    asm volatile("s_waitcnt vmcnt(0)" ::: "memory");

    // Epilogue: h = relu(acc + W1[tok] + b1); out = h . W2 + b2
    // C/D layout: n = nt*16 + col, row-in-tile = quad*4 + reg.
    const float bb2 = b2[0];
#pragma unroll
    for (int mt = 0; mt < 2; ++mt) {
#pragma unroll
        for (int reg = 0; reg < 4; ++reg) {
            int lr = mt * 16 + quad * 4 + reg;
            const float* wl = &w1c[wave][lr][0];
            float p = 0.f;
#pragma unroll
            for (int nt = 0; nt < 8; ++nt) {
                float v = acc[mt][nt][reg] + wl[nt * 16 + col] + b1v[nt];
                v = fmaxf(v, 0.f);
                p = fmaf(v, w2v[nt], p);
            }
            p += __shfl_xor(p, 1);
            p += __shfl_xor(p, 2);
            p += __shfl_xor(p, 4);
            p += __shfl_xor(p, 8);
            if (col == 0) out[row0 + lr] = p + bb2;
        }
    }
}

extern "C" void kernel_launch(void* const* d_in, const int* in_sizes, int n_in,
                              void* d_out, int out_size, void* d_ws, size_t ws_size,
                              hipStream_t stream) {
    const int*   tk  = (const int*)d_in[0];
    const float* hs0 = (const float*)d_in[1];
    const float* W1  = (const float*)d_in[2];
    const float* b1  = (const float*)d_in[3];
    const float* W2  = (const float*)d_in[4];
    const float* b2  = (const float*)d_in[5];
    float* out = (float*)d_out;
    unsigned short* Bp = (unsigned short*)d_ws;   // 768*128*2 = 196608 B

    pack_b_kernel<<<(HIDDEN * HS1) / 256, 256, 0, stream>>>(W1, Bp);

    int n_tokens = in_sizes[0];        // 16*4096 = 65536
    int grid = n_tokens / 128;         // 512 blocks: 2 blocks/CU (R5 lesson)
    classifier_kernel<<<grid, 256, 0, stream>>>(tk, hs0, W1, b1, W2, b2, Bp, out);
}

// Round 2
// 293.705 us; speedup vs baseline: 1.0462x; 1.0462x over previous
//
#include <hip/hip_runtime.h>

#define HIDDEN 768
#define VOCAB  32000
#define HS1    128
#define NSTAGE 24          // 24 stages x 32 k (one MFMA K-step per stage)
#define LSTRIDE 36         // floats per LDS row (144 B; 36 % 32 == 4 -> conflict-free b128 phases)

typedef __attribute__((ext_vector_type(8))) short bf16x8;
typedef __attribute__((ext_vector_type(4))) float f32x4;

// fp32 -> bf16 bits, round-to-nearest-even
__device__ __forceinline__ unsigned short f2bf(float f) {
    union { float f; unsigned u; } x; x.f = f;
    unsigned r = x.u + 0x7fffu + ((x.u >> 16) & 1u);
    return (unsigned short)(r >> 16);
}

// Pack W1[VOCAB:VOCAB+768, 0:128] into bf16 MFMA B-fragment order.
// Coalesced contiguous READ of W1, scattered 2-B writes (fire-and-forget).
// Bp[((ks*8+nt)*64+lane)*8+j] = B[k=ks*32+(lane>>4)*8+j][n=nt*16+(lane&15)].
__global__ void pack_b_kernel(const float* __restrict__ W1,
                              unsigned short* __restrict__ Bp) {
    int tid = blockIdx.x * 256 + threadIdx.x;   // 0 .. 98303
    float v = W1[(size_t)VOCAB * HS1 + tid];
    int k = tid >> 7;                            // 0..767
    int n = tid & 127;
    int ks = k >> 5, kr = k & 31;
    int quad = kr >> 3, j = kr & 7;
    int nt = n >> 4, c = n & 15;
    int lane = quad * 16 + c;
    Bp[(((ks * 8 + nt) * 64 + lane) << 3) + j] = f2bf(v);
}

// One wave = 32 token rows (2 m-tiles) x N=128 (8 n-tiles), K=768.
// grid=512 (2 blocks/CU — R5: 1 block/CU de-saturates HBM).
// R6 POST-MORTEM: direct fragment-order global A-loads regressed +15 µs
// (32-B-strided 16-B accesses = 50% line utilization per instruction);
// the LDS staging IS the coalescing transform. Reverted.
// R7: two changes inside the proven R5 skeleton:
//   (1) 3-deep register prefetch (gA/gB/gC): min in-flight at the lstore
//       vmcnt-wait rises 1->2 stages (32->64 KB/CU), issue distance 2->3.
//   (2) fragment ds_reads BEFORE lstore: DS is in-order per wave, so the
//       old lstore->ds_read order put {vmcnt wait + ds_write} on the MFMA
//       critical path every stage. cur's data landed last stage; read first.
__launch_bounds__(256, 2)
__global__ void classifier_kernel(const int* __restrict__ tk,
                                  const float* __restrict__ hs0,
                                  const float* __restrict__ W1,
                                  const float* __restrict__ b1,
                                  const float* __restrict__ W2,
                                  const float* __restrict__ b2,
                                  const unsigned short* __restrict__ Bp,
                                  float* __restrict__ out) {
    __shared__ float lds[4][2][32 * LSTRIDE];   // 36864 B / block

    const int lane = threadIdx.x & 63;
    const int wave = threadIdx.x >> 6;      // 0..3
    const int quad = lane >> 4;             // 0..3
    const int col  = lane & 15;             // 0..15
    const int row0 = (blockIdx.x * 4 + wave) * 32;

    float* buf0 = &lds[wave][0][0];
    float* buf1 = &lds[wave][1][0];

    // Staging mapping: instr i (0..3), lane l -> row = i*8 + (l>>3),
    // float offset (l&7)*4. 8 consecutive lanes cover one row's 128-B slab.
    const int srow = lane >> 3;             // 0..7
    const int scol = (lane & 7) * 4;        // 0,4,..,28
    const float* gbase = hs0 + (size_t)row0 * HIDDEN;

    // Prefetch the 8 token ids this lane's epilogue needs.
    int toks[8];
#pragma unroll
    for (int mt = 0; mt < 2; ++mt)
#pragma unroll
        for (int reg = 0; reg < 4; ++reg)
            toks[mt * 4 + reg] = tk[row0 + mt * 16 + quad * 4 + reg];

    f32x4 acc[2][8];
#pragma unroll
    for (int mt = 0; mt < 2; ++mt)
#pragma unroll
        for (int nt = 0; nt < 8; ++nt)
            acc[mt][nt] = (f32x4){0.f, 0.f, 0.f, 0.f};

    // Three staging register buffers -> three gload stages in flight per wave.
    f32x4 gA[4], gB[4], gC[4];
    auto gload = [&](f32x4* g, int s) {
#pragma unroll
        for (int i = 0; i < 4; ++i) {
            const float* p = gbase + (size_t)(i * 8 + srow) * HIDDEN + s * 32 + scol;
            g[i] = __builtin_nontemporal_load((const f32x4*)p);
        }
    };
    auto lstore = [&](float* buf, const f32x4* g) {
#pragma unroll
        for (int i = 0; i < 4; ++i)
            *(f32x4*)(buf + (i * 8 + srow) * LSTRIDE + scol) = g[i];
    };

    const unsigned short* pb0 = Bp + lane * 8;
    auto loadB = [&](int kstep, bf16x8* b) {
        const unsigned short* pb = pb0 + kstep * 4096;
#pragma unroll
        for (int nt = 0; nt < 4; ++nt) {
            b[nt]     = *(const bf16x8*)(pb + nt * 512);
            b[nt + 4] = *(const bf16x8*)(pb + 2048 + nt * 512);
        }
    };

    auto cvt8 = [&](f32x4 lo, f32x4 hi) {
        bf16x8 r;
        r[0] = (short)f2bf(lo[0]); r[1] = (short)f2bf(lo[1]);
        r[2] = (short)f2bf(lo[2]); r[3] = (short)f2bf(lo[3]);
        r[4] = (short)f2bf(hi[0]); r[5] = (short)f2bf(hi[1]);
        r[6] = (short)f2bf(hi[2]); r[7] = (short)f2bf(hi[3]);
        return r;
    };

    // body(s): read A fragments of stage s from `cur` (written last stage —
    // DS in-order per wave, no barrier needed); then store stage s+1 from
    // `gs` (vmcnt wait sits off the MFMA path), then reload gs with s+4.
    // Steady state: stages s+2, s+3, s+4 in flight concurrently (12 KB/wave).
    auto stage_body = [&](int s, float* cur, float* alt, f32x4* gs,
                          const bf16x8* bc, bf16x8* bn) {
        if (s + 1 < NSTAGE) loadB(s + 1, bn);
        // A fragments: lane -> A[m=col][k=quad*8+j], m-tile 1 at +16 rows.
        const float* p0 = cur + col * LSTRIDE + quad * 8;
        const float* p1 = p0 + 16 * LSTRIDE;
        f32x4 a0l = *(const f32x4*)p0, a0h = *(const f32x4*)(p0 + 4);
        f32x4 a1l = *(const f32x4*)p1, a1h = *(const f32x4*)(p1 + 4);
        bf16x8 af0 = cvt8(a0l, a0h);
        bf16x8 af1 = cvt8(a1l, a1h);
        if (s + 1 < NSTAGE) lstore(alt, gs);
        if (s + 4 < NSTAGE) gload(gs, s + 4);
#pragma unroll
        for (int nt = 0; nt < 8; ++nt) {
            acc[0][nt] = __builtin_amdgcn_mfma_f32_16x16x32_bf16(af0, bc[nt], acc[0][nt], 0, 0, 0);
            acc[1][nt] = __builtin_amdgcn_mfma_f32_16x16x32_bf16(af1, bc[nt], acc[1][nt], 0, 0, 0);
        }
    };

    // Prologue: stages 0,1,2 -> gA,gB,gC; store stage 0, reload gA with 3.
    // (bfrA/bfrB: NOT b0/b1 — parameter-name collision, R3.)
    bf16x8 bfrA[8], bfrB[8];
    gload(gA, 0);
    gload(gB, 1);
    gload(gC, 2);
    lstore(buf0, gA);        // waits on gA only; gB,gC remain outstanding
    gload(gA, 3);
    loadB(0, bfrA);

    // Register buffer for stage t is g[t % 3]; body(s) stores stage s+1 ->
    // uses g[(s+1)%3] and reloads it with s+4 (same residue). Unroll 6
    // (lcm of 2 LDS bufs x 3 reg bufs); NSTAGE=24 divides evenly.
#pragma unroll 1
    for (int s = 0; s < NSTAGE; s += 6) {
        stage_body(s,     buf0, buf1, gB, bfrA, bfrB);
        stage_body(s + 1, buf1, buf0, gC, bfrB, bfrA);
        stage_body(s + 2, buf0, buf1, gA, bfrA, bfrB);
        stage_body(s + 3, buf1, buf0, gB, bfrB, bfrA);
        stage_body(s + 4, buf0, buf1, gC, bfrA, bfrB);
        stage_body(s + 5, buf1, buf0, gA, bfrB, bfrA);
    }

    // Epilogue: h = relu(acc + W1[tok] + b1); out = h . W2 + b2
    // C/D layout: n = nt*16 + col, row-in-tile = quad*4 + reg.
    const float bb2 = b2[0];
    float b1v[8], w2v[8];
#pragma unroll
    for (int nt = 0; nt < 8; ++nt) {
        b1v[nt] = b1[nt * 16 + col];
        w2v[nt] = W2[nt * 16 + col];
    }
#pragma unroll
    for (int mt = 0; mt < 2; ++mt) {
#pragma unroll
        for (int reg = 0; reg < 4; ++reg) {
            int r = row0 + mt * 16 + quad * 4 + reg;
            const float* wrow = W1 + (size_t)toks[mt * 4 + reg] * HS1;
            float p = 0.f;
#pragma unroll
            for (int nt = 0; nt < 8; ++nt) {
                float v = acc[mt][nt][reg] + wrow[nt * 16 + col] + b1v[nt];
                v = fmaxf(v, 0.f);
                p = fmaf(v, w2v[nt], p);
            }
            p += __shfl_xor(p, 1);
            p += __shfl_xor(p, 2);
            p += __shfl_xor(p, 4);
            p += __shfl_xor(p, 8);
            if (col == 0) out[r] = p + bb2;
        }
    }
}

extern "C" void kernel_launch(void* const* d_in, const int* in_sizes, int n_in,
                              void* d_out, int out_size, void* d_ws, size_t ws_size,
                              hipStream_t stream) {
    const int*   tk  = (const int*)d_in[0];
    const float* hs0 = (const float*)d_in[1];
    const float* W1  = (const float*)d_in[2];
    const float* b1  = (const float*)d_in[3];
    const float* W2  = (const float*)d_in[4];
    const float* b2  = (const float*)d_in[5];
    float* out = (float*)d_out;
    unsigned short* Bp = (unsigned short*)d_ws;   // 768*128*2 = 196608 B

    pack_b_kernel<<<(HIDDEN * HS1) / 256, 256, 0, stream>>>(W1, Bp);

    int n_tokens = in_sizes[0];        // 16*4096 = 65536
    int grid = n_tokens / 128;         // 512 blocks: 2 blocks/CU (R5 lesson)
    classifier_kernel<<<grid, 256, 0, stream>>>(tk, hs0, W1, b1, W2, b2, Bp, out);
}